// Round 6
// baseline (25133.626 us; speedup 1.0000x reference)
//
#include <hip/hip_runtime.h>
#include <hip/hip_bf16.h>
#include <cstddef>
#include <cstdint>

#define HDIM 512
#define NNODES 1024
#define NEDGES 16384
#define BATCH 32
#define SEQ 1024
#define DIN 128

#define RLX __ATOMIC_RELAXED
#define AGT __HIP_MEMORY_SCOPE_AGENT

// ---------------------------------------------------------------------------
// Precompute: AWp[d][j] = sum_{e: dst_e=d} Wp[src_e][j]
// ---------------------------------------------------------------------------
__global__ void scatter_awp_kernel(const float* __restrict__ Wp,
                                   const int* __restrict__ src,
                                   const int* __restrict__ dst,
                                   float* __restrict__ AWp) {
    int e = blockIdx.x;        // 16384 blocks
    int c = threadIdx.x;       // 256 threads, 2 cols each
    int s = src[e], d = dst[e];
    atomicAdd(&AWp[d * HDIM + c],        Wp[s * HDIM + c]);
    atomicAdd(&AWp[d * HDIM + 256 + c],  Wp[s * HDIM + 256 + c]);
}

__global__ void scatter_abp_kernel(const float* __restrict__ bp,
                                   const int* __restrict__ src,
                                   const int* __restrict__ dst,
                                   float* __restrict__ Abp) {
    int e = blockIdx.x * blockDim.x + threadIdx.x;
    if (e < NEDGES) atomicAdd(&Abp[dst[e]], bp[src[e]]);
}

// b_eff[i] = bias[i] + bu[i] + sum_d Wu[i][d] * Abp[d]
__global__ void beff_kernel(const float* __restrict__ Wu,
                            const float* __restrict__ Abp,
                            const float* __restrict__ bias,
                            const float* __restrict__ bu,
                            float* __restrict__ beff) {
    int i = threadIdx.x;       // 512 threads, 1 block
    float s = 0.f;
    for (int d = 0; d < NNODES; ++d) s += Wu[i * NNODES + d] * Abp[d];
    beff[i] = bias[i] + bu[i] + s;
}

// ---------------------------------------------------------------------------
// fp32 tiled GEMM: C[m][n] = sum_k A[m][k] * B_(k,n)  (+ optional addend)
//   TB == 0 : B is (K x N) row-major
//   TB == 1 : B is (N x K) row-major (i.e. compute A @ B^T)
// ---------------------------------------------------------------------------
template <int TB>
__global__ __launch_bounds__(256) void gemm64(const float* __restrict__ A,
                                              const float* __restrict__ B,
                                              float* __restrict__ C,
                                              const float* __restrict__ addend,
                                              int M, int N, int K) {
    const int bn = blockIdx.x, bm = blockIdx.y;
    const int tid = threadIdx.x;
    const int tx = tid & 15, ty = tid >> 4;
    const int m0 = bm * 64, n0 = bn * 64;

    __shared__ float As[16][68];   // [kk][m]
    __shared__ float Bs[16][68];   // [kk][n]

    float acc[4][4] = {};

    for (int k0 = 0; k0 < K; k0 += 16) {
        {   // A tile 64x16 -> As[kk][m]
            int kk = tid & 15, m = tid >> 4;
            #pragma unroll
            for (int i = 0; i < 4; ++i)
                As[kk][m + 16 * i] = A[(size_t)(m0 + m + 16 * i) * K + k0 + kk];
        }
        if (TB == 0) {
            int n = tid & 63, kk = tid >> 6;
            #pragma unroll
            for (int i = 0; i < 4; ++i)
                Bs[kk + 4 * i][n] = B[(size_t)(k0 + kk + 4 * i) * N + n0 + n];
        } else {
            int kk = tid & 15, n = tid >> 4;
            #pragma unroll
            for (int i = 0; i < 4; ++i)
                Bs[kk][n + 16 * i] = B[(size_t)(n0 + n + 16 * i) * K + k0 + kk];
        }
        __syncthreads();
        #pragma unroll
        for (int kk = 0; kk < 16; ++kk) {
            float4 a4 = *reinterpret_cast<const float4*>(&As[kk][ty * 4]);
            float4 b4 = *reinterpret_cast<const float4*>(&Bs[kk][tx * 4]);
            float av[4] = {a4.x, a4.y, a4.z, a4.w};
            float bv[4] = {b4.x, b4.y, b4.z, b4.w};
            #pragma unroll
            for (int i = 0; i < 4; ++i)
                #pragma unroll
                for (int j = 0; j < 4; ++j)
                    acc[i][j] += av[i] * bv[j];
        }
        __syncthreads();
    }
    #pragma unroll
    for (int i = 0; i < 4; ++i) {
        int m = m0 + ty * 4 + i;
        #pragma unroll
        for (int j = 0; j < 4; ++j) {
            int n = n0 + tx * 4 + j;
            float v = acc[i][j];
            if (addend) v += addend[(size_t)m * N + n];
            C[(size_t)m * N + n] = v;
        }
    }
}

// ---------------------------------------------------------------------------
// DPP 64-lane sum on the VALU pipe. Stages 1-5 are R5's verified reduce32;
// stage 6 (row_bcast:31, row_mask 0xc) folds lane31's lower-half sum into
// rows 2,3 -> lane 63 holds the full 64-lane sum.
// ---------------------------------------------------------------------------
template <int CTRL, int RMASK, bool BC>
__device__ __forceinline__ float dpp_add(float x) {
    int t = __builtin_amdgcn_update_dpp(0, __float_as_int(x), CTRL, RMASK, 0xf, BC);
    return x + __int_as_float(t);
}

__device__ __forceinline__ float reduce64(float x) {
    x = dpp_add<0x111, 0xf, true>(x);   // row_shr:1
    x = dpp_add<0x112, 0xf, true>(x);   // row_shr:2
    x = dpp_add<0x114, 0xf, true>(x);   // row_shr:4
    x = dpp_add<0x118, 0xf, true>(x);   // row_shr:8
    x = dpp_add<0x142, 0xa, false>(x);  // row_bcast:15 -> rows 1,3
    x = dpp_add<0x143, 0xc, false>(x);  // row_bcast:31 -> rows 2,3
    return x;                            // lane 63 = sum of all 64 lanes
}

__device__ __forceinline__ float fast_tanh(float x) {
    float e = __expf(2.0f * x);         // v_exp path; exact at saturation
    return 1.0f - 2.0f / (e + 1.0f);
}

// ---------------------------------------------------------------------------
// Barrier-free recurrent scan. Grid (32 batch, 16 rowgroups), 256 threads
// (4 autonomous waves). Wave = 8 rows x 512 cols of one batch element:
//   lane l owns cols {l+64k} AND loads exactly h-positions {l+64k} from the
//   tagged slots -> operands align; NO LDS, NO __syncthreads.
// Tagged (h,step) 8B relaxed agent atomics (R3-proven); monotonic-tag
// induction makes parity-slot reuse and reload-all sweeps safe: tag t+2 is
// only ever written after every wave's step-t poll completed. Tag prefetch
// for t+1 issued at end of step t; u prefetched one full step ahead.
// Per-step critical path ~= store-visibility + poll-detect + ~250cy VALU.
// ---------------------------------------------------------------------------
__launch_bounds__(256, 2)   // VGPR cap 128 -> 8 waves/CU -> all 2048 resident
__global__ void scan_kernel(const float* __restrict__ Weff,
                            const float* __restrict__ beff,
                            float* __restrict__ u_ys,               // (B,S,H) in/out
                            unsigned long long* __restrict__ hpair, // [2][B][H]
                            float leak) {
    const int b    = blockIdx.x;           // 0..31
    const int rg   = blockIdx.y;           // 0..15
    const int wv   = threadIdx.x >> 6;     // 0..3
    const int lane = threadIdx.x & 63;
    const int rowbase = rg * 32 + wv * 8;
    const bool storer = (lane == 63);
    const size_t SLOTS = (size_t)BATCH * HDIM;

    // weights: w[r][k] = Weff[rowbase+r][lane + 64k]  (coalesced one-time load)
    float w[8][8];
    #pragma unroll
    for (int r = 0; r < 8; ++r)
        #pragma unroll
        for (int k = 0; k < 8; ++k)
            w[r][k] = Weff[(size_t)(rowbase + r) * HDIM + lane + 64 * k];

    float be[8];
    #pragma unroll
    for (int r = 0; r < 8; ++r) be[r] = beff[rowbase + r];

    const float lk = leak, olk = 1.0f - leak;
    float* ub = u_ys + (size_t)b * SEQ * HDIM;
    unsigned long long* hb = hpair + (size_t)b * HDIM;

    float hold[8];
    #pragma unroll
    for (int r = 0; r < 8; ++r) hold[r] = 0.f;

    // prefetch tags + u for t=0 (slot 0 holds tag 0 / h=0 from the memset)
    unsigned long long vp[8];
    #pragma unroll
    for (int k = 0; k < 8; ++k)
        vp[k] = __hip_atomic_load(hb + lane + 64 * k, RLX, AGT);
    float4 ua = make_float4(0.f, 0.f, 0.f, 0.f);
    float4 ubx = make_float4(0.f, 0.f, 0.f, 0.f);
    if (storer) {
        ua  = *reinterpret_cast<const float4*>(ub + rowbase);
        ubx = *reinterpret_cast<const float4*>(ub + rowbase + 4);
    }

    for (int t = 0; t < SEQ; ++t) {
        const unsigned tt = (unsigned)t;
        const unsigned long long* sp = hb + (size_t)(t & 1) * SLOTS + lane;

        // verify prefetched pairs; on any miss re-sweep all 8 (pipelined)
        for (;;) {
            bool miss = false;
            #pragma unroll
            for (int k = 0; k < 8; ++k)
                miss |= ((unsigned)(vp[k] >> 32) != tt);
            if (!miss) break;
            #pragma unroll
            for (int k = 0; k < 8; ++k)
                vp[k] = __hip_atomic_load(sp + 64 * k, RLX, AGT);
        }
        float h[8];
        #pragma unroll
        for (int k = 0; k < 8; ++k) h[k] = __uint_as_float((unsigned)vp[k]);

        // 8 rows x 8 owned cols of FMA, then 64-lane DPP reduce per row
        float acc[8];
        #pragma unroll
        for (int r = 0; r < 8; ++r) {
            float a = 0.f;
            #pragma unroll
            for (int k = 0; k < 8; ++k) a += w[r][k] * h[k];
            acc[r] = a;
        }
        #pragma unroll
        for (int r = 0; r < 8; ++r) acc[r] = reduce64(acc[r]);

        if (storer) {   // lane 63 holds all 8 row sums
            float uu[8] = {ua.x, ua.y, ua.z, ua.w, ubx.x, ubx.y, ubx.z, ubx.w};
            float n[8];
            #pragma unroll
            for (int r = 0; r < 8; ++r) {
                n[r] = olk * hold[r] + lk * fast_tanh(acc[r] + uu[r] + be[r]);
                hold[r] = n[r];
            }
            const unsigned long long tg = ((unsigned long long)(tt + 1)) << 32;
            unsigned long long* hw = hb + (size_t)((t + 1) & 1) * SLOTS + rowbase;
            #pragma unroll
            for (int r = 0; r < 8; ++r)
                __hip_atomic_store(hw + r, tg | __float_as_uint(n[r]), RLX, AGT);
            // ys output, in place over u
            float* yp = ub + (size_t)t * HDIM + rowbase;
            *reinterpret_cast<float4*>(yp)     = make_float4(n[0], n[1], n[2], n[3]);
            *reinterpret_cast<float4*>(yp + 4) = make_float4(n[4], n[5], n[6], n[7]);
            // u prefetch for t+1 (full step of latency cover)
            if (t + 1 < SEQ) {
                const float* up = ub + (size_t)(t + 1) * HDIM + rowbase;
                ua  = *reinterpret_cast<const float4*>(up);
                ubx = *reinterpret_cast<const float4*>(up + 4);
            }
        }
        // tag prefetch for t+1 (issued after our stores; mismatches re-poll)
        const unsigned long long* spn = hb + (size_t)((t + 1) & 1) * SLOTS + lane;
        #pragma unroll
        for (int k = 0; k < 8; ++k)
            vp[k] = __hip_atomic_load(spn + 64 * k, RLX, AGT);
    }
}

// ---------------------------------------------------------------------------
extern "C" void kernel_launch(void* const* d_in, const int* in_sizes, int n_in,
                              void* d_out, int out_size, void* d_ws, size_t ws_size,
                              hipStream_t stream) {
    const float* x      = (const float*)d_in[0];
    const int*   edges  = (const int*)d_in[1];
    const float* W_in0  = (const float*)d_in[2];
    const float* W_res0 = (const float*)d_in[3];
    const float* bias0  = (const float*)d_in[4];
    const float* Wp0    = (const float*)d_in[5];
    const float* bp0    = (const float*)d_in[6];
    const float* Wu0    = (const float*)d_in[7];
    const float* bu0    = (const float*)d_in[8];
    const float* W_in1  = (const float*)d_in[9];
    const float* W_res1 = (const float*)d_in[10];
    const float* bias1  = (const float*)d_in[11];
    const float* Wp1    = (const float*)d_in[12];
    const float* bp1    = (const float*)d_in[13];
    const float* Wu1    = (const float*)d_in[14];
    const float* bu1    = (const float*)d_in[15];

    const int* src = edges;
    const int* dst = edges + NEDGES;
    float* out = (float*)d_out;

    // workspace layout
    char* base = (char*)d_ws;
    float* ws_u  = (float*)base;                 // 32*1024*512*4 = 67,108,864
    char* p = base + (size_t)67108864;
    float* AWp   = (float*)p;  p += 2097152;     // 1024*512*4
    float* Abp   = (float*)p;  p += 4096;        // 1024*4
    float* Weff0 = (float*)p;  p += 1048576;     // 512*512*4
    float* Weff1 = (float*)p;  p += 1048576;
    float* beff0 = (float*)p;  p += 2048;
    float* beff1 = (float*)p;  p += 2048;
    unsigned long long* hpair = (unsigned long long*)p;  // 2*32*512*8 = 262144
    p += 262144;

    // ---- layer 0 effective weights ----
    hipMemsetAsync(AWp, 0, 2097152 + 4096, stream);
    scatter_awp_kernel<<<NEDGES, 256, 0, stream>>>(Wp0, src, dst, AWp);
    scatter_abp_kernel<<<NEDGES / 256, 256, 0, stream>>>(bp0, src, dst, Abp);
    gemm64<0><<<dim3(8, 8), 256, 0, stream>>>(Wu0, AWp, Weff0, W_res0, 512, 512, 1024);
    beff_kernel<<<1, 512, 0, stream>>>(Wu0, Abp, bias0, bu0, beff0);

    // ---- layer 1 effective weights ----
    hipMemsetAsync(AWp, 0, 2097152 + 4096, stream);
    scatter_awp_kernel<<<NEDGES, 256, 0, stream>>>(Wp1, src, dst, AWp);
    scatter_abp_kernel<<<NEDGES / 256, 256, 0, stream>>>(bp1, src, dst, Abp);
    gemm64<0><<<dim3(8, 8), 256, 0, stream>>>(Wu1, AWp, Weff1, W_res1, 512, 512, 1024);
    beff_kernel<<<1, 512, 0, stream>>>(Wu1, Abp, bias1, bu1, beff1);

    // ---- u0 = x @ W_in0^T : (32768 x 128) @ (512 x 128)^T ----
    gemm64<1><<<dim3(512 / 64, 32768 / 64), 256, 0, stream>>>(
        x, W_in0, ws_u, nullptr, BATCH * SEQ, HDIM, DIN);

    // ---- layer 0 scan (in place over ws_u) ----
    hipMemsetAsync(hpair, 0, 262144, stream);   // tags 0, h0 = 0
    scan_kernel<<<dim3(BATCH, 16), 256, 0, stream>>>(Weff0, beff0, ws_u, hpair, 0.1f);

    // ---- u1 = ys0 @ W_in1^T : (32768 x 512) @ (512 x 512)^T -> d_out ----
    gemm64<1><<<dim3(512 / 64, 32768 / 64), 256, 0, stream>>>(
        ws_u, W_in1, out, nullptr, BATCH * SEQ, HDIM, HDIM);

    // ---- layer 1 scan (in place over d_out) ----
    hipMemsetAsync(hpair, 0, 262144, stream);
    scan_kernel<<<dim3(BATCH, 16), 256, 0, stream>>>(Weff1, beff1, out, hpair, 0.15f);
}

// Round 7
// 7342.433 us; speedup vs baseline: 3.4231x; 3.4231x over previous
//
#include <hip/hip_runtime.h>
#include <hip/hip_bf16.h>
#include <cstddef>
#include <cstdint>

#define HDIM 512
#define NNODES 1024
#define NEDGES 16384
#define BATCH 32
#define SEQ 1024
#define DIN 128
#define RINGD 8

#define RLX __ATOMIC_RELAXED
#define AGT __HIP_MEMORY_SCOPE_AGENT

// ---------------------------------------------------------------------------
// Precompute: AWp[d][j] = sum_{e: dst_e=d} Wp[src_e][j]
// ---------------------------------------------------------------------------
__global__ void scatter_awp_kernel(const float* __restrict__ Wp,
                                   const int* __restrict__ src,
                                   const int* __restrict__ dst,
                                   float* __restrict__ AWp) {
    int e = blockIdx.x;
    int c = threadIdx.x;
    int s = src[e], d = dst[e];
    atomicAdd(&AWp[d * HDIM + c],       Wp[s * HDIM + c]);
    atomicAdd(&AWp[d * HDIM + 256 + c], Wp[s * HDIM + 256 + c]);
}

__global__ void scatter_abp_kernel(const float* __restrict__ bp,
                                   const int* __restrict__ src,
                                   const int* __restrict__ dst,
                                   float* __restrict__ Abp) {
    int e = blockIdx.x * blockDim.x + threadIdx.x;
    if (e < NEDGES) atomicAdd(&Abp[dst[e]], bp[src[e]]);
}

__global__ void beff_kernel(const float* __restrict__ Wu,
                            const float* __restrict__ Abp,
                            const float* __restrict__ bias,
                            const float* __restrict__ bu,
                            float* __restrict__ beff) {
    int i = threadIdx.x;
    float s = 0.f;
    for (int d = 0; d < NNODES; ++d) s += Wu[i * NNODES + d] * Abp[d];
    beff[i] = bias[i] + bu[i] + s;
}

__global__ void tobf16_kernel(const float* __restrict__ in,
                              ushort* __restrict__ out, int n) {
    int i = blockIdx.x * blockDim.x + threadIdx.x;
    if (i < n) {
        __hip_bfloat16 h = __float2bfloat16(in[i]);
        out[i] = *reinterpret_cast<ushort*>(&h);
    }
}

// ---------------------------------------------------------------------------
// fp32 tiled GEMM (prologue): C = A @ B (+addend); TB==1 -> B is (N x K) = B^T
// ---------------------------------------------------------------------------
template <int TB>
__global__ __launch_bounds__(256) void gemm64(const float* __restrict__ A,
                                              const float* __restrict__ B,
                                              float* __restrict__ C,
                                              const float* __restrict__ addend,
                                              int M, int N, int K) {
    const int bn = blockIdx.x, bm = blockIdx.y;
    const int tid = threadIdx.x;
    const int tx = tid & 15, ty = tid >> 4;
    const int m0 = bm * 64, n0 = bn * 64;

    __shared__ float As[16][68];
    __shared__ float Bs[16][68];

    float acc[4][4] = {};

    for (int k0 = 0; k0 < K; k0 += 16) {
        {
            int kk = tid & 15, m = tid >> 4;
            #pragma unroll
            for (int i = 0; i < 4; ++i)
                As[kk][m + 16 * i] = A[(size_t)(m0 + m + 16 * i) * K + k0 + kk];
        }
        if (TB == 0) {
            int n = tid & 63, kk = tid >> 6;
            #pragma unroll
            for (int i = 0; i < 4; ++i)
                Bs[kk + 4 * i][n] = B[(size_t)(k0 + kk + 4 * i) * N + n0 + n];
        } else {
            int kk = tid & 15, n = tid >> 4;
            #pragma unroll
            for (int i = 0; i < 4; ++i)
                Bs[kk][n + 16 * i] = B[(size_t)(n0 + n + 16 * i) * K + k0 + kk];
        }
        __syncthreads();
        #pragma unroll
        for (int kk = 0; kk < 16; ++kk) {
            float4 a4 = *reinterpret_cast<const float4*>(&As[kk][ty * 4]);
            float4 b4 = *reinterpret_cast<const float4*>(&Bs[kk][tx * 4]);
            float av[4] = {a4.x, a4.y, a4.z, a4.w};
            float bv[4] = {b4.x, b4.y, b4.z, b4.w};
            #pragma unroll
            for (int i = 0; i < 4; ++i)
                #pragma unroll
                for (int j = 0; j < 4; ++j)
                    acc[i][j] += av[i] * bv[j];
        }
        __syncthreads();
    }
    #pragma unroll
    for (int i = 0; i < 4; ++i) {
        int m = m0 + ty * 4 + i;
        #pragma unroll
        for (int j = 0; j < 4; ++j) {
            int n = n0 + tx * 4 + j;
            float v = acc[i][j];
            if (addend) v += addend[(size_t)m * N + n];
            C[(size_t)m * N + n] = v;
        }
    }
}

// ---------------------------------------------------------------------------
// DPP half-wave sum (R5-verified): lanes 31/63 hold their 32-lane half sums.
// ---------------------------------------------------------------------------
template <int CTRL, int RMASK, bool BC>
__device__ __forceinline__ float dpp_add(float x) {
    int t = __builtin_amdgcn_update_dpp(0, __float_as_int(x), CTRL, RMASK, 0xf, BC);
    return x + __int_as_float(t);
}

__device__ __forceinline__ float reduce32(float x) {
    x = dpp_add<0x111, 0xf, true>(x);
    x = dpp_add<0x112, 0xf, true>(x);
    x = dpp_add<0x114, 0xf, true>(x);
    x = dpp_add<0x118, 0xf, true>(x);
    x = dpp_add<0x142, 0xa, false>(x);
    return x;
}

__device__ __forceinline__ float fast_tanh(float x) {
    float e = __expf(2.0f * x);
    return 1.0f - 2.0f / (e + 1.0f);
}

__device__ __forceinline__ float bflo(unsigned q) { return __uint_as_float(q << 16); }
__device__ __forceinline__ float bfhi(unsigned q) { return __uint_as_float(q & 0xffff0000u); }

// ---------------------------------------------------------------------------
// Fused dual-layer pipelined scan. Grid (8 slices, 32 batch, 2 layers), 512t.
// blockIdx.z==0 (L0): R5 structure + fused u1[t-1] = W_in1[slice rows]·ys0(t-1)
//   (ys0(t-1) = h0(t) = this step's hs). W_in1 slice read as bf16 from global
//   (L2-hot, issued before the poll). u1 goes into a depth-8 tagged ring.
// blockIdx.z==1 (L1): R5 structure; u comes from the u1 ring (tid<64 poll ->
//   LDS, double-buffered); writes ys1 straight to d_out. prog1[b][s]=t+1 after
//   consuming u1[t] gives L0 causal back-pressure (checked 8 steps in arrears,
//   never spins in steady state).
// All exchange: (tag,value) u64 relaxed agent atomics (R3/R5-proven induction;
// hpair consumers are exactly the 8 same-layer WGs of the batch).
// ---------------------------------------------------------------------------
__launch_bounds__(512, 4)
__global__ void scan2_kernel(const float* __restrict__ Weff0,
                             const float* __restrict__ beff0,
                             const float* __restrict__ Weff1,
                             const float* __restrict__ beff1,
                             const ushort* __restrict__ Wbf,    // bf16 W_in1 [512][512]
                             const float* __restrict__ u0,      // (B,S,H)
                             float* __restrict__ out,           // (B,S,H) ys1
                             unsigned long long* __restrict__ hp0,
                             unsigned long long* __restrict__ hp1,
                             unsigned long long* __restrict__ u1r, // [RINGD][B][H]
                             unsigned int* __restrict__ prog1) {   // [B*8]
    const int slice = blockIdx.x;
    const int b = blockIdx.y;
    const int tid = threadIdx.x;
    const int c = tid & 31;
    const int hw = tid >> 5;
    const int rloc = hw * 4;
    const int rowbase = slice * 64 + rloc;
    const bool storer = (c == 31);
    const size_t SLOTS = (size_t)BATCH * HDIM;

    __shared__ float hs[2][HDIM];
    __shared__ float u1s[2][64];

    if (blockIdx.z == 0) {
        // ================= layer 0 =================
        const float lk = 0.1f, olk = 0.9f;
        float4 w[4][4];
        #pragma unroll
        for (int r = 0; r < 4; ++r)
            #pragma unroll
            for (int k = 0; k < 4; ++k)
                w[r][k] = *reinterpret_cast<const float4*>(
                    Weff0 + (size_t)(rowbase + r) * HDIM + 4 * (c + 32 * k));
        float4 be4 = make_float4(0.f, 0.f, 0.f, 0.f);
        if (storer) be4 = *reinterpret_cast<const float4*>(beff0 + rowbase);

        const ushort* wbs = Wbf + (size_t)slice * 64 * HDIM;
        const float* u0b = u0 + (size_t)b * SEQ * HDIM;
        unsigned long long* h0b = hp0 + (size_t)b * HDIM;
        unsigned int* pg = prog1 + b * 8 + slice;
        float4 hold = make_float4(0.f, 0.f, 0.f, 0.f);

        for (int t = 0; t <= SEQ; ++t) {
            // W_in1 bf16 slice loads (for u1) -- issued before the poll
            uint2 wl[4][4];
            #pragma unroll
            for (int r = 0; r < 4; ++r)
                #pragma unroll
                for (int k = 0; k < 4; ++k)
                    wl[r][k] = *reinterpret_cast<const uint2*>(
                        wbs + (size_t)(rloc + r) * HDIM + 4 * (c + 32 * k));
            // u0 prefetch (storer lanes)
            float4 u4 = make_float4(0.f, 0.f, 0.f, 0.f);
            if (storer && t < SEQ)
                u4 = *reinterpret_cast<const float4*>(u0b + (size_t)t * HDIM + rowbase);

            // poll h0(t)
            const unsigned long long* sp = h0b + (size_t)(t & 1) * SLOTS + tid;
            unsigned long long v;
            do { v = __hip_atomic_load(sp, RLX, AGT); } while ((unsigned)(v >> 32) != (unsigned)t);
            hs[t & 1][tid] = __uint_as_float((unsigned)v);

            // ring back-pressure: storing u1[t-1] overwrites u1[t-1-RINGD]
            if (tid == 0 && t >= RINGD + 1) {
                while ((int)__hip_atomic_load(pg, RLX, AGT) < t - RINGD) {}
            }
            __syncthreads();

            const float* h = hs[t & 1];
            float a0 = 0, a1 = 0, a2 = 0, a3 = 0;
            float g0 = 0, g1 = 0, g2 = 0, g3 = 0;
            #pragma unroll
            for (int k = 0; k < 4; ++k) {
                float4 h4 = *reinterpret_cast<const float4*>(h + 4 * (c + 32 * k));
                a0 += w[0][k].x * h4.x + w[0][k].y * h4.y + w[0][k].z * h4.z + w[0][k].w * h4.w;
                a1 += w[1][k].x * h4.x + w[1][k].y * h4.y + w[1][k].z * h4.z + w[1][k].w * h4.w;
                a2 += w[2][k].x * h4.x + w[2][k].y * h4.y + w[2][k].z * h4.z + w[2][k].w * h4.w;
                a3 += w[3][k].x * h4.x + w[3][k].y * h4.y + w[3][k].z * h4.z + w[3][k].w * h4.w;
                g0 += bflo(wl[0][k].x) * h4.x + bfhi(wl[0][k].x) * h4.y
                    + bflo(wl[0][k].y) * h4.z + bfhi(wl[0][k].y) * h4.w;
                g1 += bflo(wl[1][k].x) * h4.x + bfhi(wl[1][k].x) * h4.y
                    + bflo(wl[1][k].y) * h4.z + bfhi(wl[1][k].y) * h4.w;
                g2 += bflo(wl[2][k].x) * h4.x + bfhi(wl[2][k].x) * h4.y
                    + bflo(wl[2][k].y) * h4.z + bfhi(wl[2][k].y) * h4.w;
                g3 += bflo(wl[3][k].x) * h4.x + bfhi(wl[3][k].x) * h4.y
                    + bflo(wl[3][k].y) * h4.z + bfhi(wl[3][k].y) * h4.w;
            }

            if (t < SEQ) {   // own recurrence (critical path first)
                a0 = reduce32(a0); a1 = reduce32(a1);
                a2 = reduce32(a2); a3 = reduce32(a3);
                if (storer) {
                    float n0 = olk * hold.x + lk * fast_tanh(a0 + u4.x + be4.x);
                    float n1 = olk * hold.y + lk * fast_tanh(a1 + u4.y + be4.y);
                    float n2 = olk * hold.z + lk * fast_tanh(a2 + u4.z + be4.z);
                    float n3 = olk * hold.w + lk * fast_tanh(a3 + u4.w + be4.w);
                    hold = make_float4(n0, n1, n2, n3);
                    const unsigned long long tg = ((unsigned long long)(unsigned)(t + 1)) << 32;
                    unsigned long long* hwp = h0b + (size_t)((t + 1) & 1) * SLOTS + rowbase;
                    __hip_atomic_store(hwp + 0, tg | __float_as_uint(n0), RLX, AGT);
                    __hip_atomic_store(hwp + 1, tg | __float_as_uint(n1), RLX, AGT);
                    __hip_atomic_store(hwp + 2, tg | __float_as_uint(n2), RLX, AGT);
                    __hip_atomic_store(hwp + 3, tg | __float_as_uint(n3), RLX, AGT);
                }
            }
            if (t >= 1) {    // u1[t-1] (fire-and-forget for L1)
                g0 = reduce32(g0); g1 = reduce32(g1);
                g2 = reduce32(g2); g3 = reduce32(g3);
                if (storer) {
                    const unsigned long long tg = ((unsigned long long)(unsigned)t) << 32;
                    unsigned long long* up = u1r + (size_t)((t - 1) & (RINGD - 1)) * SLOTS
                                           + (size_t)b * HDIM + rowbase;
                    __hip_atomic_store(up + 0, tg | __float_as_uint(g0), RLX, AGT);
                    __hip_atomic_store(up + 1, tg | __float_as_uint(g1), RLX, AGT);
                    __hip_atomic_store(up + 2, tg | __float_as_uint(g2), RLX, AGT);
                    __hip_atomic_store(up + 3, tg | __float_as_uint(g3), RLX, AGT);
                }
            }
        }
    } else {
        // ================= layer 1 =================
        const float lk = 0.15f, olk = 0.85f;
        float4 w[4][4];
        #pragma unroll
        for (int r = 0; r < 4; ++r)
            #pragma unroll
            for (int k = 0; k < 4; ++k)
                w[r][k] = *reinterpret_cast<const float4*>(
                    Weff1 + (size_t)(rowbase + r) * HDIM + 4 * (c + 32 * k));
        float4 be4 = make_float4(0.f, 0.f, 0.f, 0.f);
        if (storer) be4 = *reinterpret_cast<const float4*>(beff1 + rowbase);

        unsigned long long* h1b = hp1 + (size_t)b * HDIM;
        float* ob = out + (size_t)b * SEQ * HDIM;
        float4 hold = make_float4(0.f, 0.f, 0.f, 0.f);

        for (int t = 0; t < SEQ; ++t) {
            // poll h1(t)
            const unsigned long long* sp = h1b + (size_t)(t & 1) * SLOTS + tid;
            unsigned long long v;
            do { v = __hip_atomic_load(sp, RLX, AGT); } while ((unsigned)(v >> 32) != (unsigned)t);
            hs[t & 1][tid] = __uint_as_float((unsigned)v);
            // poll u1[t] (64 rows of this slice)
            if (tid < 64) {
                const unsigned long long* up = u1r + (size_t)(t & (RINGD - 1)) * SLOTS
                                             + (size_t)b * HDIM + slice * 64 + tid;
                unsigned long long v2;
                do { v2 = __hip_atomic_load(up, RLX, AGT); } while ((unsigned)(v2 >> 32) != (unsigned)(t + 1));
                u1s[t & 1][tid] = __uint_as_float((unsigned)v2);
            }
            __syncthreads();
            if (tid == 0)
                __hip_atomic_store(prog1 + b * 8 + slice, (unsigned)(t + 1), RLX, AGT);

            const float* h = hs[t & 1];
            float a0 = 0, a1 = 0, a2 = 0, a3 = 0;
            #pragma unroll
            for (int k = 0; k < 4; ++k) {
                float4 h4 = *reinterpret_cast<const float4*>(h + 4 * (c + 32 * k));
                a0 += w[0][k].x * h4.x + w[0][k].y * h4.y + w[0][k].z * h4.z + w[0][k].w * h4.w;
                a1 += w[1][k].x * h4.x + w[1][k].y * h4.y + w[1][k].z * h4.z + w[1][k].w * h4.w;
                a2 += w[2][k].x * h4.x + w[2][k].y * h4.y + w[2][k].z * h4.z + w[2][k].w * h4.w;
                a3 += w[3][k].x * h4.x + w[3][k].y * h4.y + w[3][k].z * h4.z + w[3][k].w * h4.w;
            }
            a0 = reduce32(a0); a1 = reduce32(a1);
            a2 = reduce32(a2); a3 = reduce32(a3);

            if (storer) {
                float4 uu = *reinterpret_cast<const float4*>(&u1s[t & 1][rloc]);
                float n0 = olk * hold.x + lk * fast_tanh(a0 + uu.x + be4.x);
                float n1 = olk * hold.y + lk * fast_tanh(a1 + uu.y + be4.y);
                float n2 = olk * hold.z + lk * fast_tanh(a2 + uu.z + be4.z);
                float n3 = olk * hold.w + lk * fast_tanh(a3 + uu.w + be4.w);
                hold = make_float4(n0, n1, n2, n3);
                const unsigned long long tg = ((unsigned long long)(unsigned)(t + 1)) << 32;
                unsigned long long* hwp = h1b + (size_t)((t + 1) & 1) * SLOTS + rowbase;
                __hip_atomic_store(hwp + 0, tg | __float_as_uint(n0), RLX, AGT);
                __hip_atomic_store(hwp + 1, tg | __float_as_uint(n1), RLX, AGT);
                __hip_atomic_store(hwp + 2, tg | __float_as_uint(n2), RLX, AGT);
                __hip_atomic_store(hwp + 3, tg | __float_as_uint(n3), RLX, AGT);
                *reinterpret_cast<float4*>(ob + (size_t)t * HDIM + rowbase) =
                    make_float4(n0, n1, n2, n3);
            }
        }
    }
}

// ---------------------------------------------------------------------------
extern "C" void kernel_launch(void* const* d_in, const int* in_sizes, int n_in,
                              void* d_out, int out_size, void* d_ws, size_t ws_size,
                              hipStream_t stream) {
    const float* x      = (const float*)d_in[0];
    const int*   edges  = (const int*)d_in[1];
    const float* W_in0  = (const float*)d_in[2];
    const float* W_res0 = (const float*)d_in[3];
    const float* bias0  = (const float*)d_in[4];
    const float* Wp0    = (const float*)d_in[5];
    const float* bp0    = (const float*)d_in[6];
    const float* Wu0    = (const float*)d_in[7];
    const float* bu0    = (const float*)d_in[8];
    const float* W_in1  = (const float*)d_in[9];
    const float* W_res1 = (const float*)d_in[10];
    const float* bias1  = (const float*)d_in[11];
    const float* Wp1    = (const float*)d_in[12];
    const float* bp1    = (const float*)d_in[13];
    const float* Wu1    = (const float*)d_in[14];
    const float* bu1    = (const float*)d_in[15];

    const int* src = edges;
    const int* dst = edges + NEDGES;
    float* out = (float*)d_out;

    // workspace layout (total identical to prior rounds: 71,573,504 B)
    char* base = (char*)d_ws;
    float* ws_u = (float*)base;                       // u0: 67,108,864
    char* q = base + (size_t)67108864;                // 2,101,248-byte union region
    float* AWp = (float*)q;                           // prologue: 2,097,152
    float* Abp = (float*)(q + 2097152);               // prologue: 4,096
    // scan-time overlay of the same region:
    ushort* Wbf = (ushort*)q;                                     // 524,288
    unsigned long long* hp0 = (unsigned long long*)(q + 524288);  // 262,144
    unsigned long long* hp1 = (unsigned long long*)(q + 786432);  // 262,144
    unsigned long long* u1r = (unsigned long long*)(q + 1048576); // 1,048,576
    unsigned int* prog1 = (unsigned int*)(q + 2097152);           // 1,024 (over Abp)
    char* p2 = q + 2101248;
    float* Weff0 = (float*)p2;                        // 1,048,576
    float* Weff1 = (float*)(p2 + 1048576);            // 1,048,576
    float* beff0 = (float*)(p2 + 2097152);            // 2,048
    float* beff1 = (float*)(p2 + 2099200);            // 2,048

    // ---- layer 0 effective weights ----
    hipMemsetAsync(AWp, 0, 2097152 + 4096, stream);
    scatter_awp_kernel<<<NEDGES, 256, 0, stream>>>(Wp0, src, dst, AWp);
    scatter_abp_kernel<<<NEDGES / 256, 256, 0, stream>>>(bp0, src, dst, Abp);
    gemm64<0><<<dim3(8, 8), 256, 0, stream>>>(Wu0, AWp, Weff0, W_res0, 512, 512, 1024);
    beff_kernel<<<1, 512, 0, stream>>>(Wu0, Abp, bias0, bu0, beff0);

    // ---- layer 1 effective weights ----
    hipMemsetAsync(AWp, 0, 2097152 + 4096, stream);
    scatter_awp_kernel<<<NEDGES, 256, 0, stream>>>(Wp1, src, dst, AWp);
    scatter_abp_kernel<<<NEDGES / 256, 256, 0, stream>>>(bp1, src, dst, Abp);
    gemm64<0><<<dim3(8, 8), 256, 0, stream>>>(Wu1, AWp, Weff1, W_res1, 512, 512, 1024);
    beff_kernel<<<1, 512, 0, stream>>>(Wu1, Abp, bias1, bu1, beff1);

    // ---- u0 = x @ W_in0^T ----
    gemm64<1><<<dim3(512 / 64, 32768 / 64), 256, 0, stream>>>(
        x, W_in0, ws_u, nullptr, BATCH * SEQ, HDIM, DIN);

    // ---- overlay: W_in1 -> bf16, zero sync structures (AWp/Abp now dead) ----
    tobf16_kernel<<<1024, 256, 0, stream>>>(W_in1, Wbf, HDIM * HDIM);
    hipMemsetAsync(q + 524288, 0, 1573888, stream);   // hp0, hp1, u1r, prog1

    // ---- fused pipelined dual-layer scan ----
    scan2_kernel<<<dim3(8, BATCH, 2), 512, 0, stream>>>(
        Weff0, beff0, Weff1, beff1, Wbf, ws_u, out, hp0, hp1, u1r, prog1);
}